// Round 6
// baseline (131.377 us; speedup 1.0000x reference)
//
#include <hip/hip_runtime.h>
#include <math.h>

#define D_BINS 59
#define CO     64
#define CI     256
#define NB     4
#define NC     6
#define H_IMG  16
#define W_IMG  44
#define HW     704            // H_IMG * W_IMG
#define NPIX   (NB*NC*HW)     // 16896
#define XD     128
#define YD     128
#define ZD     7
#define NOUT   123            // D_BINS + CO
#define PXB    66             // pixels per k_head block tile
#define THR    768            // k_head threads: 12 waves
#define XW     66             // X row width (64 cols + 2 pad)

typedef float v2f __attribute__((ext_vector_type(2)));

// ---------------------------------------------------------------------------
// Double-precision rigid-transform inverse (matches np.linalg.inv to ~1e-15,
// avoiding depth-bin boundary flips downstream).
// ---------------------------------------------------------------------------
__device__ void inv_rigid(const float* __restrict__ M, float* __restrict__ o) {
    double a = M[0], b = M[1], c = M[2], t0 = M[3];
    double d = M[4], e = M[5], f = M[6], t1 = M[7];
    double g = M[8], h = M[9], ii = M[10], t2 = M[11];
    double A00 = e*ii - f*h, A01 = c*h - b*ii, A02 = b*f - c*e;
    double A10 = f*g - d*ii, A11 = a*ii - c*g, A12 = c*d - a*f;
    double A20 = d*h - e*g,  A21 = b*g - a*h,  A22 = a*e - b*d;
    double det = a*A00 + b*A10 + c*A20;
    double inv = 1.0 / det;
    double r00 = A00*inv, r01 = A01*inv, r02 = A02*inv;
    double r10 = A10*inv, r11 = A11*inv, r12 = A12*inv;
    double r20 = A20*inv, r21 = A21*inv, r22 = A22*inv;
    o[0] = (float)r00; o[1] = (float)r01; o[2]  = (float)r02;
    o[3] = (float)(-(r00*t0 + r01*t1 + r02*t2));
    o[4] = (float)r10; o[5] = (float)r11; o[6]  = (float)r12;
    o[7] = (float)(-(r10*t0 + r11*t1 + r12*t2));
    o[8] = (float)r20; o[9] = (float)r21; o[10] = (float)r22;
    o[11] = (float)(-(r20*t0 + r21*t1 + r22*t2));
}

// ---------------------------------------------------------------------------
// Kernel 1: prep. W (123x256) -> wt2, k-pair-interleaved + transposed:
//   wt2[(k/2)*256 + o*2 + (k&1)], o zero-padded to 128. Unchanged.
// ---------------------------------------------------------------------------
__global__ __launch_bounds__(256) void k_pre(
    const float* __restrict__ wd, const float* __restrict__ c2e,
    float* __restrict__ wt2, float* __restrict__ e2c) {
    const int o = blockIdx.x;   // 0..127
    const int k = threadIdx.x;  // 0..255
    float v = (o < NOUT) ? wd[(size_t)o * CI + k] : 0.f;
    wt2[(size_t)(k >> 1) * 256 + o * 2 + (k & 1)] = v;
    if (blockIdx.x == 0 && k < NB * NC)
        inv_rigid(c2e + k * 16, e2c + k * 12);
}

// ---------------------------------------------------------------------------
// Kernel 2: depth/feat head. NEW this round: K-SPLIT for 2x latency cover.
// Grid (256,2) x 768 thr (12 waves). Waves 0..7 main: (o-strip j = wv&3,
// k-half kh = wv>>2); waves 8..11 edge: (px 64/65, kh). A for ALL 256
// channels is staged ONCE (67.6 KB, kp-interleaved, identical layout),
// then each wave runs its 64 k2-steps with ZERO k-loop barriers.
// 67.8 KB LDS -> 2 blocks/CU -> 24 waves/CU (6/SIMD), double R4's 3/SIMD:
// the ~200cyc s_load(K$-miss->L2) per 32cyc-VALU k2 step now has 6 waves
// rotating instead of 3. k-half partials combined in a deterministic
// two-phase LDS epilogue (h0 write, barrier, h1 add + bias) -> one fp32
// reassociation vs baseline (~1e-6 rel), accepted.
// ---------------------------------------------------------------------------
__global__ __launch_bounds__(THR) void k_head(
    const float* __restrict__ img, const float* __restrict__ wt2,
    const float* __restrict__ bd, float* __restrict__ depth_out,
    float* __restrict__ feat_ws) {
    __shared__ float smem[128 * 132 + PXB];  // A[128 kp][132]; X aliases; S tail
    float* S = smem + 128 * 132;

    const int tid  = threadIdx.x;
    const int wv   = tid >> 6;               // 0..11
    const int ln   = tid & 63;
    const int p0   = blockIdx.x * PXB;
    const int half = blockIdx.y;             // 0 or 1
    const int ob   = half << 6;              // 0 or 64
    const bool is_main = (wv < 8);
    const int j    = wv & 3;                 // main o-strip
    const int kh   = is_main ? (wv >> 2) : ((wv - 8) >> 1);
    const int o0   = __builtin_amdgcn_readfirstlane(ob + (j << 4));
    const int k2b  = __builtin_amdgcn_readfirstlane(kh << 6);   // k2 base
    const int epx  = __builtin_amdgcn_readfirstlane(64 + ((wv - 8) & 1));

    // ---- stage ALL of A: 256 ch x 66 px, kp-interleaved; one barrier ----
    for (int idx = tid; idx < 256 * PXB; idx += THR) {   // 22 iters exactly
        int kl = idx / PXB, px = idx - kl * PXB;
        int p = p0 + px;
        int bn = p / HW, hw = p - bn * HW;
        smem[(kl >> 1) * 132 + px * 2 + (kl & 1)] =
            img[((size_t)bn * CI + kl) * HW + hw];
    }
    __syncthreads();

    v2f acc[16];                             // main: o-strip of 16
#pragma unroll
    for (int q = 0; q < 16; ++q) acc[q] = (v2f)(0.f);
    v2f acc2 = (v2f)(0.f);                   // edge: o = ob + ln

    if (is_main) {
#pragma unroll 4
        for (int k2i = 0; k2i < 64; ++k2i) {
            int k2 = k2b + k2i;
            v2f a = *(const v2f*)(smem + k2 * 132 + ln * 2);   // stride-8B: free
            const v2f* w = (const v2f*)(wt2 + (size_t)k2 * 256) + o0;  // s_load
#pragma unroll
            for (int q = 0; q < 16; ++q)
                acc[q] = __builtin_elementwise_fma(a, w[q], acc[q]);
        }
    } else {
#pragma unroll 4
        for (int k2i = 0; k2i < 64; ++k2i) {
            int k2 = k2b + k2i;
            v2f a = *(const v2f*)(smem + k2 * 132 + epx * 2);  // broadcast
            const float* w = wt2 + (size_t)k2 * 256;
            v2f w0 = {w[(ob + ln) * 2], w[(ob + ln) * 2 + 1]}; // dwordx2
            acc2 = __builtin_elementwise_fma(a, w0, acc2);
        }
    }
    __syncthreads();   // all A reads done -> X may alias A

    // ---- two-phase k-half combine into X[66][XW], col = o - ob ----
    float* X = smem;
    if (kh == 0) {
        if (is_main) {
#pragma unroll
            for (int q = 0; q < 16; ++q) {
                int o = o0 + q;
                if (o < NOUT)
                    X[ln * XW + (o - ob)] = acc[q].x + acc[q].y;
            }
        } else {
            int o = ob + ln;
            if (o < NOUT)
                X[epx * XW + ln] = acc2.x + acc2.y;
        }
    }
    __syncthreads();
    if (kh == 1) {
        if (is_main) {
#pragma unroll
            for (int q = 0; q < 16; ++q) {
                int o = o0 + q;
                if (o < NOUT) {
                    int col = o - ob;
                    X[ln * XW + col] =
                        (X[ln * XW + col] + (acc[q].x + acc[q].y)) + bd[o];
                }
            }
        } else {
            int o = ob + ln;
            if (o < NOUT)
                X[epx * XW + ln] =
                    (X[epx * XW + ln] + (acc2.x + acc2.y)) + bd[o];
        }
    }
    __syncthreads();

    if (half == 0) {
        // feat channels 0..4 (o = 59..63)
        if (tid < PXB * 5) {
            int p = tid / 5, c = tid - p * 5;
            feat_ws[(size_t)(p0 + p) * CO + c] = X[p * XW + 59 + c];
        }
        // softmax over cols 0..58, one thread per pixel
        if (tid < PXB) {
            float* row = X + tid * XW;
            float m = row[0];
            for (int o = 1; o < D_BINS; ++o) m = fmaxf(m, row[o]);
            float s = 0.f;
            for (int o = 0; o < D_BINS; ++o) {
                float e = __expf(row[o] - m);
                row[o] = e;
                s += e;
            }
            S[tid] = 1.f / s;
        }
        __syncthreads();
        // depth: block region contiguous [p0*59, (p0+66)*59) -> coalesced
        for (int g = tid; g < PXB * D_BINS; g += THR) {
            int p = g / D_BINS;
            int o = g - p * D_BINS;
            depth_out[(size_t)p0 * D_BINS + g] = X[p * XW + o] * S[p];
        }
    } else {
        // feat channels 5..63 (o = 64..122 at cols 0..58)
        for (int g = tid; g < PXB * D_BINS; g += THR) {
            int p = g / D_BINS;
            int col = g - p * D_BINS;
            feat_ws[(size_t)(p0 + p) * CO + 5 + col] = X[p * XW + col];
        }
    }
}

// ---------------------------------------------------------------------------
// Kernel 3: project voxels, gather depth weight + feat, splat to BEV.
// Round-0 (124 us baseline) version, byte-identical.
// ---------------------------------------------------------------------------
__global__ __launch_bounds__(256) void k_splat(
    const float* __restrict__ e2c, const float* __restrict__ Kmat,
    const float* __restrict__ depth_g, const float* __restrict__ feat_ws,
    float* __restrict__ bev) {
    __shared__ int   hw_s[ZD][64];
    __shared__ float wgt_s[ZD][64];

    const int tx = threadIdx.x;          // 0..63 -> x
    const int cq = threadIdx.y;          // 0..3  -> channel quarter / z-slice
    const int x = blockIdx.x * 64 + tx;
    const int y = blockIdx.y;
    const int b = blockIdx.z;
    const float wx = (float)x * 0.8f + (-51.2f);
    const float wy = (float)y * 0.8f + (-51.2f);

    float acc[16];
#pragma unroll
    for (int m = 0; m < 16; ++m) acc[m] = 0.f;

    for (int n = 0; n < NC; ++n) {
        const int bn = b * NC + n;
        const float* E = e2c + bn * 12;
        const float* Km = Kmat + bn * 9;
        const float k00 = Km[0], k01 = Km[1], k02 = Km[2];
        const float k10 = Km[3], k11 = Km[4], k12 = Km[5];
        const float e02 = E[2], e12 = E[6], e22 = E[10];
        const float bx0 = E[0] * wx + E[1] * wy + E[3];
        const float bx1 = E[4] * wx + E[5] * wy + E[7];
        const float bx2 = E[8] * wx + E[9] * wy + E[11];

        // ---- projection phase: thread (tx,cq) owns z = cq and cq+4 ----
#pragma unroll
        for (int zz = 0; zz < 2; ++zz) {
            const int z = cq + zz * 4;
            if (z < ZD) {
                const float wz = -2.5f + (float)z;
                const float cx = bx0 + e02 * wz;
                const float cy = bx1 + e12 * wz;
                const float cz = bx2 + e22 * wz;
                const float zs = fmaxf(cz, 0.1f);
                const float rz = 1.0f / zs;         // IEEE divide
                const float xn = cx * rz;
                const float yn = cy * rz;
                const float fu = (k00 * xn + k01 * yn + k02) * 0.0625f;
                const float fv = (k10 * xn + k11 * yn + k12) * 0.0625f;
                const int bin = (int)(cz - 1.0f);   // trunc, matches astype(int32)
                const bool valid = (fu >= 0.f) & (fu < (float)W_IMG) &
                                   (fv >= 0.f) & (fv < (float)H_IMG) &
                                   (cz > 0.5f) & (bin >= 0) & (bin < D_BINS);
                int hw = -1;
                float wgt = 0.f;
                if (valid) {
                    int u = (int)fu;                // valid => in range
                    int v = (int)fv;
                    hw = v * W_IMG + u;
                    wgt = depth_g[((size_t)bn * HW + hw) * D_BINS + bin];
                }
                hw_s[z][tx] = hw;
                wgt_s[z][tx] = wgt;
            }
        }
        __syncthreads();

        // ---- accumulate phase: z ascending (same FMA order as baseline) ----
#pragma unroll
        for (int z = 0; z < ZD; ++z) {
            const int hw = hw_s[z][tx];       // 4 cq threads same addr: broadcast
            if (hw >= 0) {
                const float wgt = wgt_s[z][tx];
                const float4* fp =
                    (const float4*)(feat_ws + ((size_t)bn * HW + hw) * CO + cq * 16);
                float4 f0 = fp[0], f1 = fp[1], f2 = fp[2], f3 = fp[3];
                acc[0]  = fmaf(wgt, f0.x, acc[0]);
                acc[1]  = fmaf(wgt, f0.y, acc[1]);
                acc[2]  = fmaf(wgt, f0.z, acc[2]);
                acc[3]  = fmaf(wgt, f0.w, acc[3]);
                acc[4]  = fmaf(wgt, f1.x, acc[4]);
                acc[5]  = fmaf(wgt, f1.y, acc[5]);
                acc[6]  = fmaf(wgt, f1.z, acc[6]);
                acc[7]  = fmaf(wgt, f1.w, acc[7]);
                acc[8]  = fmaf(wgt, f2.x, acc[8]);
                acc[9]  = fmaf(wgt, f2.y, acc[9]);
                acc[10] = fmaf(wgt, f2.z, acc[10]);
                acc[11] = fmaf(wgt, f2.w, acc[11]);
                acc[12] = fmaf(wgt, f3.x, acc[12]);
                acc[13] = fmaf(wgt, f3.y, acc[13]);
                acc[14] = fmaf(wgt, f3.z, acc[14]);
                acc[15] = fmaf(wgt, f3.w, acc[15]);
            }
        }
        __syncthreads();   // LDS reused next n
    }
    // out[b][c][y][x], c = cq*16 + m; 64 lanes = consecutive x -> coalesced
    float* ob = bev + (((size_t)b * CO + cq * 16) * YD + y) * XD + x;
#pragma unroll
    for (int m = 0; m < 16; ++m) ob[(size_t)m * YD * XD] = acc[m];
}

extern "C" void kernel_launch(void* const* d_in, const int* in_sizes, int n_in,
                              void* d_out, int out_size, void* d_ws, size_t ws_size,
                              hipStream_t stream) {
    const float* img  = (const float*)d_in[0];  // (B,N,256,16,44)
    const float* c2e  = (const float*)d_in[1];  // (B,N,4,4)
    const float* Kmat = (const float*)d_in[2];  // (B,N,3,3)
    const float* wd   = (const float*)d_in[3];  // (123,256)
    const float* bd   = (const float*)d_in[4];  // (123,)
    float* bev = (float*)d_out;                         // (B,64,128,128)
    float* depth_out = bev + (size_t)NB * CO * YD * XD; // (B,N,16,44,59)
    float* feat_ws = (float*)d_ws;                      // NPIX*64 floats
    float* wt2 = feat_ws + (size_t)NPIX * CO;           // 128*256 floats
    float* e2c = wt2 + 128 * 256;                       // 24*12 floats

    k_pre<<<128, 256, 0, stream>>>(wd, c2e, wt2, e2c);
    k_head<<<dim3(256, 2), THR, 0, stream>>>(img, wt2, bd, depth_out, feat_ws);
    k_splat<<<dim3(2, YD, NB), dim3(64, 4, 1), 0, stream>>>(e2c, Kmat, depth_out,
                                                            feat_ws, bev);
}

// Round 7
// 125.020 us; speedup vs baseline: 1.0508x; 1.0508x over previous
//
#include <hip/hip_runtime.h>
#include <math.h>

#define D_BINS 59
#define CO     64
#define CI     256
#define NB     4
#define NC     6
#define H_IMG  16
#define W_IMG  44
#define HW     704            // H_IMG * W_IMG
#define NPIX   (NB*NC*HW)     // 16896
#define XD     128
#define YD     128
#define ZD     7
#define NOUT   123            // D_BINS + CO
#define PXT    32             // pixels per k_head tile: 16896 = 528 * 32; 704 = 22*32
#define XW     132            // X row width: 128 o + 4 pad

typedef float v2f __attribute__((ext_vector_type(2)));

// ---------------------------------------------------------------------------
// Double-precision rigid-transform inverse (matches np.linalg.inv to ~1e-15,
// avoiding depth-bin boundary flips downstream).
// ---------------------------------------------------------------------------
__device__ void inv_rigid(const float* __restrict__ M, float* __restrict__ o) {
    double a = M[0], b = M[1], c = M[2], t0 = M[3];
    double d = M[4], e = M[5], f = M[6], t1 = M[7];
    double g = M[8], h = M[9], ii = M[10], t2 = M[11];
    double A00 = e*ii - f*h, A01 = c*h - b*ii, A02 = b*f - c*e;
    double A10 = f*g - d*ii, A11 = a*ii - c*g, A12 = c*d - a*f;
    double A20 = d*h - e*g,  A21 = b*g - a*h,  A22 = a*e - b*d;
    double det = a*A00 + b*A10 + c*A20;
    double inv = 1.0 / det;
    double r00 = A00*inv, r01 = A01*inv, r02 = A02*inv;
    double r10 = A10*inv, r11 = A11*inv, r12 = A12*inv;
    double r20 = A20*inv, r21 = A21*inv, r22 = A22*inv;
    o[0] = (float)r00; o[1] = (float)r01; o[2]  = (float)r02;
    o[3] = (float)(-(r00*t0 + r01*t1 + r02*t2));
    o[4] = (float)r10; o[5] = (float)r11; o[6]  = (float)r12;
    o[7] = (float)(-(r10*t0 + r11*t1 + r12*t2));
    o[8] = (float)r20; o[9] = (float)r21; o[10] = (float)r22;
    o[11] = (float)(-(r20*t0 + r21*t1 + r22*t2));
}

// ---------------------------------------------------------------------------
// Kernel 1: prep. W (123x256) -> wt2, k-pair-interleaved + transposed:
//   wt2[(k/2)*256 + o*2 + (k&1)], o zero-padded to 128. Unchanged.
// ---------------------------------------------------------------------------
__global__ __launch_bounds__(256) void k_pre(
    const float* __restrict__ wd, const float* __restrict__ c2e,
    float* __restrict__ wt2, float* __restrict__ e2c) {
    const int o = blockIdx.x;   // 0..127
    const int k = threadIdx.x;  // 0..255
    float v = (o < NOUT) ? wd[(size_t)o * CI + k] : 0.f;
    wt2[(size_t)(k >> 1) * 256 + o * 2 + (k & 1)] = v;
    if (blockIdx.x == 0 && k < NB * NC)
        inv_rigid(c2e + k * 16, e2c + k * 12);
}

// ---------------------------------------------------------------------------
// Kernel 2: depth/feat head. NEW this round: LANE = OUTPUT (o-pair), W on
// the VECTOR path. R6 counters (VALUBusy 30.6%, more waves made it WORSE)
// showed the scalar W path was the wall: 128B of W per k2 step can't be
// pipelined in a 112-SGPR file, and wt2 s_loads miss the local XCD L2.
// Now lane ln owns o={2ln,2ln+1}; per k2 step the wave issues ONE per-lane
// coalesced global_load_dwordx4 of the wt2 row (1KB/wave, vmcnt-pipelined,
// VGPR-rich) + 8 broadcast ds_read_b128 of A pairs + 32 v_pk_fma_f32.
// No scalar memory, no k-loop barriers. Tiles of 32 px (grid 528; tiles
// never cross a camera: 704=22*32), 4 waves = 2 px-groups x 2 k-halves,
// ~50KB LDS -> 3 blocks/CU. K-half partials combined via the R6-proven
// two-phase LDS epilogue (one f32 reassociation, previously accepted).
// ---------------------------------------------------------------------------
__global__ __launch_bounds__(256) void k_head(
    const float* __restrict__ img, const float* __restrict__ wt2,
    const float* __restrict__ bd, float* __restrict__ depth_out,
    float* __restrict__ feat_ws) {
    __shared__ float A[128 * 64];     // [k-pair][px*2+(k&1)]: 32KB
    __shared__ float Xs[PXT * XW];    // [px][o(+pad)]: 16.9KB
    __shared__ float S[PXT];

    const int tid = threadIdx.x;
    const int wv  = tid >> 6;                  // 0..3
    const int ln  = tid & 63;
    const int p0  = blockIdx.x * PXT;
    const int pw0 = (wv & 1) << 4;             // wave's first px (0 or 16)
    const int kh  = wv >> 1;                   // k-half
    const int kb  = __builtin_amdgcn_readfirstlane(kh << 6);  // k2 base

    // ---- stage A tile: 256 ch x 32 px (tile within one (b,n): 704=22*32) ----
    const int bn  = p0 / HW;                   // scalar
    const int hw0 = p0 - bn * HW;
    const float* gsrc = img + (size_t)bn * CI * HW + hw0;
#pragma unroll 8
    for (int it = 0; it < 32; ++it) {
        int idx = tid + it * 256;
        int ch = idx >> 5, px = idx & 31;      // power-of-2: no div
        A[(ch >> 1) * 64 + px * 2 + (ch & 1)] = gsrc[ch * HW + px];
    }
    __syncthreads();

    // ---- main loop: 64 k2 steps, no barriers ----
    v2f accA[16], accB[16];                    // [px] = {even-k, odd-k} sums
#pragma unroll
    for (int p = 0; p < 16; ++p) { accA[p] = (v2f)(0.f); accB[p] = (v2f)(0.f); }

#pragma unroll 2
    for (int k2i = 0; k2i < 64; ++k2i) {
        const int k2 = kb + k2i;
        // W row: per-lane 16B -> one coalesced 1KB global_load_dwordx4
        float4 w4 = *(const float4*)(wt2 + (size_t)k2 * 256 + ln * 4);
        v2f wA = {w4.x, w4.y};                 // o = 2ln
        v2f wB = {w4.z, w4.w};                 // o = 2ln+1
        const float* ar = A + k2 * 64 + pw0 * 2;   // wave-uniform
#pragma unroll
        for (int i = 0; i < 8; ++i) {
            float4 aq = *(const float4*)(ar + i * 4);  // broadcast b128: 2 px
            v2f a0 = {aq.x, aq.y};
            v2f a1 = {aq.z, aq.w};
            accA[2*i]   = __builtin_elementwise_fma(a0, wA, accA[2*i]);
            accB[2*i]   = __builtin_elementwise_fma(a0, wB, accB[2*i]);
            accA[2*i+1] = __builtin_elementwise_fma(a1, wA, accA[2*i+1]);
            accB[2*i+1] = __builtin_elementwise_fma(a1, wB, accB[2*i+1]);
        }
    }

    // ---- two-phase k-half combine into Xs[px][o] ----
    if (kh == 0) {
#pragma unroll
        for (int p = 0; p < 16; ++p) {
            v2f v = { accA[p].x + accA[p].y, accB[p].x + accB[p].y };
            *(v2f*)(Xs + (pw0 + p) * XW + 2 * ln) = v;   // stride-8B: free
        }
    }
    __syncthreads();
    if (kh == 1) {
        float b0 = (2 * ln     < NOUT) ? bd[2 * ln]     : 0.f;
        float b1 = (2 * ln + 1 < NOUT) ? bd[2 * ln + 1] : 0.f;
#pragma unroll
        for (int p = 0; p < 16; ++p) {
            v2f s = *(const v2f*)(Xs + (pw0 + p) * XW + 2 * ln);
            v2f v = { (s.x + (accA[p].x + accA[p].y)) + b0,
                      (s.y + (accB[p].x + accB[p].y)) + b1 };
            *(v2f*)(Xs + (pw0 + p) * XW + 2 * ln) = v;
        }
    }
    __syncthreads();

    // ---- feat: Xs[p][59..122] -> feat_ws; cols >=59 not touched by softmax ----
    for (int g = tid; g < PXT * CO; g += 256) {
        int p = g >> 6, c = g & 63;
        feat_ws[(size_t)(p0 + p) * CO + c] = Xs[p * XW + 59 + c];
    }
    // ---- softmax over cols 0..58, one thread per pixel ----
    if (tid < PXT) {
        float* row = Xs + tid * XW;
        float m = row[0];
        for (int o = 1; o < D_BINS; ++o) m = fmaxf(m, row[o]);
        float s = 0.f;
        for (int o = 0; o < D_BINS; ++o) {
            float e = __expf(row[o] - m);
            row[o] = e;
            s += e;
        }
        S[tid] = 1.f / s;
    }
    __syncthreads();
    // ---- depth: tile region contiguous [p0*59, (p0+32)*59) -> coalesced ----
    for (int g = tid; g < PXT * D_BINS; g += 256) {
        int p = g / D_BINS;
        int o = g - p * D_BINS;
        depth_out[(size_t)p0 * D_BINS + g] = Xs[p * XW + o] * S[p];
    }
}

// ---------------------------------------------------------------------------
// Kernel 3: project voxels, gather depth weight + feat, splat to BEV.
// Round-0 (124 us baseline) version, byte-identical.
// ---------------------------------------------------------------------------
__global__ __launch_bounds__(256) void k_splat(
    const float* __restrict__ e2c, const float* __restrict__ Kmat,
    const float* __restrict__ depth_g, const float* __restrict__ feat_ws,
    float* __restrict__ bev) {
    __shared__ int   hw_s[ZD][64];
    __shared__ float wgt_s[ZD][64];

    const int tx = threadIdx.x;          // 0..63 -> x
    const int cq = threadIdx.y;          // 0..3  -> channel quarter / z-slice
    const int x = blockIdx.x * 64 + tx;
    const int y = blockIdx.y;
    const int b = blockIdx.z;
    const float wx = (float)x * 0.8f + (-51.2f);
    const float wy = (float)y * 0.8f + (-51.2f);

    float acc[16];
#pragma unroll
    for (int m = 0; m < 16; ++m) acc[m] = 0.f;

    for (int n = 0; n < NC; ++n) {
        const int bn = b * NC + n;
        const float* E = e2c + bn * 12;
        const float* Km = Kmat + bn * 9;
        const float k00 = Km[0], k01 = Km[1], k02 = Km[2];
        const float k10 = Km[3], k11 = Km[4], k12 = Km[5];
        const float e02 = E[2], e12 = E[6], e22 = E[10];
        const float bx0 = E[0] * wx + E[1] * wy + E[3];
        const float bx1 = E[4] * wx + E[5] * wy + E[7];
        const float bx2 = E[8] * wx + E[9] * wy + E[11];

        // ---- projection phase: thread (tx,cq) owns z = cq and cq+4 ----
#pragma unroll
        for (int zz = 0; zz < 2; ++zz) {
            const int z = cq + zz * 4;
            if (z < ZD) {
                const float wz = -2.5f + (float)z;
                const float cx = bx0 + e02 * wz;
                const float cy = bx1 + e12 * wz;
                const float cz = bx2 + e22 * wz;
                const float zs = fmaxf(cz, 0.1f);
                const float rz = 1.0f / zs;         // IEEE divide
                const float xn = cx * rz;
                const float yn = cy * rz;
                const float fu = (k00 * xn + k01 * yn + k02) * 0.0625f;
                const float fv = (k10 * xn + k11 * yn + k12) * 0.0625f;
                const int bin = (int)(cz - 1.0f);   // trunc, matches astype(int32)
                const bool valid = (fu >= 0.f) & (fu < (float)W_IMG) &
                                   (fv >= 0.f) & (fv < (float)H_IMG) &
                                   (cz > 0.5f) & (bin >= 0) & (bin < D_BINS);
                int hw = -1;
                float wgt = 0.f;
                if (valid) {
                    int u = (int)fu;                // valid => in range
                    int v = (int)fv;
                    hw = v * W_IMG + u;
                    wgt = depth_g[((size_t)bn * HW + hw) * D_BINS + bin];
                }
                hw_s[z][tx] = hw;
                wgt_s[z][tx] = wgt;
            }
        }
        __syncthreads();

        // ---- accumulate phase: z ascending (same FMA order as baseline) ----
#pragma unroll
        for (int z = 0; z < ZD; ++z) {
            const int hw = hw_s[z][tx];       // 4 cq threads same addr: broadcast
            if (hw >= 0) {
                const float wgt = wgt_s[z][tx];
                const float4* fp =
                    (const float4*)(feat_ws + ((size_t)bn * HW + hw) * CO + cq * 16);
                float4 f0 = fp[0], f1 = fp[1], f2 = fp[2], f3 = fp[3];
                acc[0]  = fmaf(wgt, f0.x, acc[0]);
                acc[1]  = fmaf(wgt, f0.y, acc[1]);
                acc[2]  = fmaf(wgt, f0.z, acc[2]);
                acc[3]  = fmaf(wgt, f0.w, acc[3]);
                acc[4]  = fmaf(wgt, f1.x, acc[4]);
                acc[5]  = fmaf(wgt, f1.y, acc[5]);
                acc[6]  = fmaf(wgt, f1.z, acc[6]);
                acc[7]  = fmaf(wgt, f1.w, acc[7]);
                acc[8]  = fmaf(wgt, f2.x, acc[8]);
                acc[9]  = fmaf(wgt, f2.y, acc[9]);
                acc[10] = fmaf(wgt, f2.z, acc[10]);
                acc[11] = fmaf(wgt, f2.w, acc[11]);
                acc[12] = fmaf(wgt, f3.x, acc[12]);
                acc[13] = fmaf(wgt, f3.y, acc[13]);
                acc[14] = fmaf(wgt, f3.z, acc[14]);
                acc[15] = fmaf(wgt, f3.w, acc[15]);
            }
        }
        __syncthreads();   // LDS reused next n
    }
    // out[b][c][y][x], c = cq*16 + m; 64 lanes = consecutive x -> coalesced
    float* ob = bev + (((size_t)b * CO + cq * 16) * YD + y) * XD + x;
#pragma unroll
    for (int m = 0; m < 16; ++m) ob[(size_t)m * YD * XD] = acc[m];
}

extern "C" void kernel_launch(void* const* d_in, const int* in_sizes, int n_in,
                              void* d_out, int out_size, void* d_ws, size_t ws_size,
                              hipStream_t stream) {
    const float* img  = (const float*)d_in[0];  // (B,N,256,16,44)
    const float* c2e  = (const float*)d_in[1];  // (B,N,4,4)
    const float* Kmat = (const float*)d_in[2];  // (B,N,3,3)
    const float* wd   = (const float*)d_in[3];  // (123,256)
    const float* bd   = (const float*)d_in[4];  // (123,)
    float* bev = (float*)d_out;                         // (B,64,128,128)
    float* depth_out = bev + (size_t)NB * CO * YD * XD; // (B,N,16,44,59)
    float* feat_ws = (float*)d_ws;                      // NPIX*64 floats
    float* wt2 = feat_ws + (size_t)NPIX * CO;           // 128*256 floats
    float* e2c = wt2 + 128 * 256;                       // 24*12 floats

    k_pre<<<128, 256, 0, stream>>>(wd, c2e, wt2, e2c);
    k_head<<<528, 256, 0, stream>>>(img, wt2, bd, depth_out, feat_ws);
    k_splat<<<dim3(2, YD, NB), dim3(64, 4, 1), 0, stream>>>(e2c, Kmat, depth_out,
                                                            feat_ws, bev);
}